// Round 12
// baseline (286.478 us; speedup 1.0000x reference)
//
#include <hip/hip_runtime.h>

// CRF forward via parallel-in-time segmented scan. B=256, T<=2048, C=64.
// q_t = diag(ex_t)·E·q_{t-1} (linear) => P=64 segments per batch (SEG=32).
// K1: 256-thread block = 4 INDEPENDENT chain waves (wave w -> segment 4*sb+w),
//     zero LDS, zero barriers. Proven round-10/11 chain: 32x
//     mfma_f32_16x16x32_bf16 per step; kappa(g,i)=4g+(i&3)+16(i>>2) on BOTH
//     A(=exp(trans)) and B -> lane-local recirculation via cvt_pk.
//     NEW: depth-4 x prefetch ring (halves exposed HBM latency) and renorm
//     every 4 steps (readfirstlane/rcp/log only at group heads; scale applied
//     in the exp2 fma; exact bookkeeping Lseg -= lgr when applied).
//     f32/bf16 headroom over 4 unscaled steps: =< ~2^50 growth, safe.
// K2: one wave per batch: q <- renorm(M_s·q) over segments; lane j owns row j
//     of bf16 M (8x uint4, 1-deep prefetch), unpack = shift<<16. (proven)

#define CC 64

typedef short bf16x8 __attribute__((ext_vector_type(8)));
typedef float f32x4 __attribute__((ext_vector_type(4)));

union PackAB { int w[4]; bf16x8 v; };

__device__ __forceinline__ int cvtpk(float lo, float hi) {
    int r;
    asm("v_cvt_pk_bf16_f32 %0, %1, %2" : "=v"(r) : "v"(lo), "v"(hi));
    return r;
}
__device__ __forceinline__ float bcast0(float v) {
    return __int_as_float(__builtin_amdgcn_readfirstlane(__float_as_int(v)));
}

#define LDS_FENCE() asm volatile("s_waitcnt lgkmcnt(0)" ::: "memory")

__launch_bounds__(256, 3)
__global__ void crf_seg_kernel(const float* __restrict__ x,      // (B,T,C)
                               const float* __restrict__ trans,  // (C,C)
                               const int*   __restrict__ lens,   // (B,)
                               unsigned short* __restrict__ Mws, // (B*P,64,64) bf16
                               float* __restrict__ Ls,           // (B*P,)
                               int T, int Pseg, int P4shift, int SEG) {
    const int blk = blockIdx.x;
    const int tid = threadIdx.x;
    const int w   = tid >> 6;
    const int l   = tid & 63;
    const int b   = blk >> P4shift;
    const int s   = ((blk & ((1 << P4shift) - 1)) << 2) + w;   // 4 chains/block
    if (s >= Pseg) return;

    const int L = lens[b];
    const int tbeg = s * SEG;
    int segend = (s + 1) * SEG; if (segend > L - 1) segend = L - 1;
    const int nsteps = segend - tbeg;      // matmul steps t = tbeg+1 .. segend
    if (nsteps <= 0) return;               // per-wave exit (no barriers anywhere)

    const int c = l & 15, g = l >> 4;
    const float L2E = 1.4426950408889634f;
    const float* xb = x + (size_t)b * T * CC;

    // A frags: A[mt][ch] slot (g,i) = exp(trans[16mt+c][32ch + kappa(g,i)])
    bf16x8 A[4][2];
    #pragma unroll
    for (int mt = 0; mt < 4; ++mt) {
        const float* tr = trans + (16 * mt + c) * CC;
        #pragma unroll
        for (int ch = 0; ch < 2; ++ch) {
            float4 u = *(const float4*)(tr + 32 * ch + 4 * g);
            float4 v = *(const float4*)(tr + 32 * ch + 16 + 4 * g);
            PackAB pk;
            pk.w[0] = cvtpk(__builtin_amdgcn_exp2f(u.x * L2E), __builtin_amdgcn_exp2f(u.y * L2E));
            pk.w[1] = cvtpk(__builtin_amdgcn_exp2f(u.z * L2E), __builtin_amdgcn_exp2f(u.w * L2E));
            pk.w[2] = cvtpk(__builtin_amdgcn_exp2f(v.x * L2E), __builtin_amdgcn_exp2f(v.y * L2E));
            pk.w[3] = cvtpk(__builtin_amdgcn_exp2f(v.z * L2E), __builtin_amdgcn_exp2f(v.w * L2E));
            A[mt][ch] = pk.v;
        }
    }
    // B = identity in fragment form (verified rounds 8/10/11)
    PackAB Bf[2][4];
    #pragma unroll
    for (int ch = 0; ch < 2; ++ch)
        #pragma unroll
        for (int nt = 0; nt < 4; ++nt)
            #pragma unroll
            for (int qq = 0; qq < 4; ++qq) {
                int i0 = 2 * qq, i1 = 2 * qq + 1;
                int k0 = 32 * ch + 4 * g + (i0 & 3) + 16 * (i0 >> 2);
                int k1 = 32 * ch + 4 * g + (i1 & 3) + 16 * (i1 >> 2);
                Bf[ch][nt].w[qq] = cvtpk((k0 == 16 * nt + c) ? 1.f : 0.f,
                                         (k1 == 16 * nt + c) ? 1.f : 0.f);
            }

    // depth-4 named x prefetch ring (static indexing only)
    f32x4 XPa[4], XPb[4], XPc[4], XPd[4];
    {
        int t0_ = tbeg + 1;
        int t1_ = tbeg + 2; if (t1_ > segend) t1_ = segend;
        int t2_ = tbeg + 3; if (t2_ > segend) t2_ = segend;
        int t3_ = tbeg + 4; if (t3_ > segend) t3_ = segend;
        const float* p0 = xb + (size_t)t0_ * CC + 4 * g;
        const float* p1 = xb + (size_t)t1_ * CC + 4 * g;
        const float* p2 = xb + (size_t)t2_ * CC + 4 * g;
        const float* p3 = xb + (size_t)t3_ * CC + 4 * g;
        #pragma unroll
        for (int mt = 0; mt < 4; ++mt) {
            XPa[mt] = *(const f32x4*)(p0 + 16 * mt);
            XPb[mt] = *(const f32x4*)(p1 + 16 * mt);
            XPc[mt] = *(const f32x4*)(p2 + 16 * mt);
            XPd[mt] = *(const f32x4*)(p3 + 16 * mt);
        }
    }

    float Lseg = 0.f;
    float ns0  = 1.0f;   // lane0 holds raw D[0][0] of the latest step

    // one matmul step: M_new = diag(2^(x*L2E + LGR))·(E·M_old); M lives in Bf
    #define STEP(idx_, XP, LGR) do {                                          \
        f32x4 exr[4];                                                         \
        _Pragma("unroll")                                                     \
        for (int mt = 0; mt < 4; ++mt) {                                      \
            f32x4 xv = XP[mt];                                                \
            _Pragma("unroll")                                                 \
            for (int r = 0; r < 4; ++r)                                       \
                exr[mt][r] = __builtin_amdgcn_exp2f(fmaf(xv[r], L2E, (LGR))); \
        }                                                                     \
        {   /* refill this ring slot for step idx_+4 */                       \
            int tp = tbeg + 5 + (idx_); if (tp > segend) tp = segend;         \
            const float* xp = xb + (size_t)tp * CC + 4 * g;                   \
            _Pragma("unroll")                                                 \
            for (int mt = 0; mt < 4; ++mt)                                    \
                XP[mt] = *(const f32x4*)(xp + 16 * mt);                       \
        }                                                                     \
        _Pragma("unroll")                                                     \
        for (int nt = 0; nt < 4; ++nt) {                                      \
            f32x4 Z = {0.f, 0.f, 0.f, 0.f};                                   \
            f32x4 t0, d0, d1, d2, d3;                                         \
            t0 = __builtin_amdgcn_mfma_f32_16x16x32_bf16(A[0][0], Bf[0][nt].v, Z, 0, 0, 0);  \
            d0 = __builtin_amdgcn_mfma_f32_16x16x32_bf16(A[0][1], Bf[1][nt].v, t0, 0, 0, 0); \
            t0 = __builtin_amdgcn_mfma_f32_16x16x32_bf16(A[1][0], Bf[0][nt].v, Z, 0, 0, 0);  \
            d1 = __builtin_amdgcn_mfma_f32_16x16x32_bf16(A[1][1], Bf[1][nt].v, t0, 0, 0, 0); \
            t0 = __builtin_amdgcn_mfma_f32_16x16x32_bf16(A[2][0], Bf[0][nt].v, Z, 0, 0, 0);  \
            d2 = __builtin_amdgcn_mfma_f32_16x16x32_bf16(A[2][1], Bf[1][nt].v, t0, 0, 0, 0); \
            t0 = __builtin_amdgcn_mfma_f32_16x16x32_bf16(A[3][0], Bf[0][nt].v, Z, 0, 0, 0);  \
            d3 = __builtin_amdgcn_mfma_f32_16x16x32_bf16(A[3][1], Bf[1][nt].v, t0, 0, 0, 0); \
            if (nt == 0) ns0 = d0[0];      /* raw D[0][0], pre-scale */       \
            d0 *= exr[0]; d1 *= exr[1]; d2 *= exr[2]; d3 *= exr[3];           \
            Bf[0][nt].w[0] = cvtpk(d0[0], d0[1]);                             \
            Bf[0][nt].w[1] = cvtpk(d0[2], d0[3]);                             \
            Bf[0][nt].w[2] = cvtpk(d1[0], d1[1]);                             \
            Bf[0][nt].w[3] = cvtpk(d1[2], d1[3]);                             \
            Bf[1][nt].w[0] = cvtpk(d2[0], d2[1]);                             \
            Bf[1][nt].w[1] = cvtpk(d2[2], d2[3]);                             \
            Bf[1][nt].w[2] = cvtpk(d3[0], d3[1]);                             \
            Bf[1][nt].w[3] = cvtpk(d3[2], d3[3]);                             \
        }                                                                     \
    } while (0)

    for (int base = 0; base < nsteps; base += 4) {
        float lgr = 0.f;
        if (base > 0) {   // renorm once per 4 steps; exact bookkeeping
            float S00 = bcast0(ns0);
            float r_  = __builtin_amdgcn_rcpf(S00);
            lgr = __builtin_amdgcn_logf(r_);     // log2 of ACTUAL scale applied
            Lseg -= lgr;
        }
        STEP(base, XPa, lgr);
        if (base + 1 < nsteps) STEP(base + 1, XPb, 0.f);
        if (base + 2 < nsteps) STEP(base + 2, XPc, 0.f);
        if (base + 3 < nsteps) STEP(base + 3, XPd, 0.f);
    }
    #undef STEP

    // store M_s as bf16 row-major [row][col] + Lseg
    unsigned short* Mo = Mws + ((size_t)b * Pseg + s) * 4096;
    #pragma unroll
    for (int ch = 0; ch < 2; ++ch)
        #pragma unroll
        for (int nt = 0; nt < 4; ++nt)
            #pragma unroll
            for (int e = 0; e < 8; ++e) {
                unsigned wb = (unsigned)Bf[ch][nt].w[e >> 1];
                unsigned short hb = (e & 1) ? (unsigned short)(wb >> 16)
                                            : (unsigned short)(wb & 0xffffu);
                int row = 32 * ch + 4 * g + (e & 3) + 16 * (e >> 2);
                Mo[row * 64 + 16 * nt + c] = hb;
            }
    if (l == 0) Ls[(size_t)b * Pseg + s] = Lseg;
}

__launch_bounds__(64, 1)
__global__ void crf_apply_kernel(const float* __restrict__ x,
                                 const float* __restrict__ orig,
                                 const int*   __restrict__ lens,
                                 const unsigned short* __restrict__ Mws,
                                 const float* __restrict__ Ls,
                                 float* __restrict__ out,
                                 int T, int Pseg, int SEG) {
    const int b = blockIdx.x, j = threadIdx.x;
    __shared__ float qb[CC];
    const float L2E = 1.4426950408889634f, LN2 = 0.6931471805599453f;
    const int L = lens[b];
    const float* xb = x + (size_t)b * T * CC;

    float Mbar = (xb[0] + orig[0]) * L2E;
    float q = __builtin_amdgcn_exp2f((xb[j] + orig[j]) * L2E - Mbar);

    // 1-deep prefetch of this lane's bf16 row (row j of M_s)
    uint4 R[8];
    {
        const uint4* Ms = (const uint4*)(Mws + ((size_t)b * Pseg + 0) * 4096 + j * 64);
        #pragma unroll
        for (int i = 0; i < 8; ++i) R[i] = Ms[i];
    }

    for (int s = 0; s < Pseg; ++s) {
        int tbeg = s * SEG;
        int segend = (s + 1) * SEG; if (segend > L - 1) segend = L - 1;
        if (segend - tbeg <= 0) break;   // later segments inactive too

        uint4 Rc[8];
        #pragma unroll
        for (int i = 0; i < 8; ++i) Rc[i] = R[i];
        {   // prefetch next segment's row (clamped; garbage unused if inactive)
            int s2 = (s + 1 < Pseg) ? s + 1 : s;
            const uint4* Ms = (const uint4*)(Mws + ((size_t)b * Pseg + s2) * 4096 + j * 64);
            #pragma unroll
            for (int i = 0; i < 8; ++i) R[i] = Ms[i];
        }

        qb[j] = q;
        LDS_FENCE();

        float acc = 0.f;
        #pragma unroll
        for (int i = 0; i < 8; ++i) {
            f32x4 qv0 = *(const f32x4*)&qb[8 * i];
            f32x4 qv1 = *(const f32x4*)&qb[8 * i + 4];
            unsigned u0 = Rc[i].x, u1 = Rc[i].y, u2 = Rc[i].z, u3 = Rc[i].w;
            acc = fmaf(__uint_as_float(u0 << 16),        qv0[0], acc);
            acc = fmaf(__uint_as_float(u0 & 0xffff0000), qv0[1], acc);
            acc = fmaf(__uint_as_float(u1 << 16),        qv0[2], acc);
            acc = fmaf(__uint_as_float(u1 & 0xffff0000), qv0[3], acc);
            acc = fmaf(__uint_as_float(u2 << 16),        qv1[0], acc);
            acc = fmaf(__uint_as_float(u2 & 0xffff0000), qv1[1], acc);
            acc = fmaf(__uint_as_float(u3 << 16),        qv1[2], acc);
            acc = fmaf(__uint_as_float(u3 & 0xffff0000), qv1[3], acc);
        }
        float S = acc;
        Mbar += Ls[(size_t)b * Pseg + s];
        float p = bcast0(S);
        float r = __builtin_amdgcn_rcpf(p);
        float lgr = __builtin_amdgcn_logf(r);
        q = S * r;
        Mbar -= lgr;
        LDS_FENCE();   // reads of qb done before next overwrite
    }

    float alpha = LN2 * (Mbar + __builtin_amdgcn_logf(q));
    alpha += __shfl_xor(alpha, 1, 64);
    alpha += __shfl_xor(alpha, 2, 64);
    alpha += __shfl_xor(alpha, 4, 64);
    alpha += __shfl_xor(alpha, 8, 64);
    alpha += __shfl_xor(alpha, 16, 64);
    alpha += __shfl_xor(alpha, 32, 64);
    if (j == 0) out[b] = alpha;
}

extern "C" void kernel_launch(void* const* d_in, const int* in_sizes, int n_in,
                              void* d_out, int out_size, void* d_ws, size_t ws_size,
                              hipStream_t stream) {
    const float* x     = (const float*)d_in[0];
    const float* trans = (const float*)d_in[1];
    const float* orig  = (const float*)d_in[2];
    const int*   lens  = (const int*)d_in[3];
    float* out = (float*)d_out;

    const int B = in_sizes[3];
    const int T = in_sizes[0] / (B * CC);

    int P = 64;
    while (P > 4 && ws_size < (size_t)B * P * (4096 * 2 + 4)) P >>= 1;
    int P4shift = 0; while ((4 << P4shift) < P) ++P4shift;   // P4 = P/4
    const int SEG = (T + P - 1) / P;

    unsigned short* Mws = (unsigned short*)d_ws;
    float* Ls = (float*)(Mws + (size_t)B * P * 4096);

    crf_seg_kernel<<<B * (P >> 2), 256, 0, stream>>>(x, trans, lens, Mws, Ls,
                                                     T, P, P4shift, SEG);
    crf_apply_kernel<<<B, 64, 0, stream>>>(x, orig, lens, Mws, Ls, out, T, P, SEG);
}

// Round 13
// 207.310 us; speedup vs baseline: 1.3819x; 1.3819x over previous
//
#include <hip/hip_runtime.h>

// CRF forward via parallel-in-time segmented scan. B=256, T<=2048, C=64.
// q_t = diag(ex_t)·E·q_{t-1} (linear) => P=64 segments per batch (SEG=32).
// K1: ONE 64-thread block per (batch,segment). NEW vs round 11: the whole
//     segment's x (32 rows = 8KB) is staged into LDS up front with 8
//     concurrent coalesced loads (ONE HBM latency per wave instead of one
//     per step); the chain loop reads x via conflict-free ds_read_b128.
//     Chain itself is round-10/11 verbatim (proven): 32x
//     mfma_f32_16x16x32_bf16 per step; kappa(g,i)=4g+(i&3)+16(i>>2) on BOTH
//     A(=exp(trans)) and B -> lane-local recirculation via cvt_pk; renorm
//     per step folded into the exp2 arg, exact bookkeeping Lseg -= lgr.
// K2: one wave per batch: q <- renorm(M_s·q) over segments; lane j owns
//     row j of bf16 M (8x uint4, 1-deep prefetch). (proven rounds 10-12)

#define CC 64

typedef short bf16x8 __attribute__((ext_vector_type(8)));
typedef float f32x4 __attribute__((ext_vector_type(4)));

union PackAB { int w[4]; bf16x8 v; };

__device__ __forceinline__ int cvtpk(float lo, float hi) {
    int r;
    asm("v_cvt_pk_bf16_f32 %0, %1, %2" : "=v"(r) : "v"(lo), "v"(hi));
    return r;
}
__device__ __forceinline__ float bcast0(float v) {
    return __int_as_float(__builtin_amdgcn_readfirstlane(__float_as_int(v)));
}

#define LDS_FENCE() asm volatile("s_waitcnt lgkmcnt(0)" ::: "memory")

__launch_bounds__(64, 2)
__global__ void crf_seg_kernel(const float* __restrict__ x,      // (B,T,C)
                               const float* __restrict__ trans,  // (C,C)
                               const int*   __restrict__ lens,   // (B,)
                               unsigned short* __restrict__ Mws, // (B*P,64,64) bf16
                               float* __restrict__ Ls,           // (B*P,)
                               int T, int Pseg, int Pshift, int SEG) {
    const int blk = blockIdx.x;
    const int b = blk >> Pshift;
    const int s = blk & (Pseg - 1);
    const int L = lens[b];
    const int tbeg = s * SEG;
    int segend = (s + 1) * SEG; if (segend > L - 1) segend = L - 1;
    const int nsteps = segend - tbeg;      // matmul steps t = tbeg+1 .. segend
    if (nsteps <= 0) return;

    const int l = threadIdx.x;
    const int c = l & 15, g = l >> 4;
    const float L2E = 1.4426950408889634f;
    const float* xb = x + (size_t)b * T * CC;

    __shared__ float xl[32][CC];           // 8 KiB: rows t = tbeg+1 .. tbeg+32

    // ---- stage segment x into LDS: 8 concurrent coalesced loads ----
    {
        const int rl = l >> 4;             // row within 4-row group
        const int cl = (l & 15) * 4;       // col chunk
        f32x4 st[8];
        #pragma unroll
        for (int i = 0; i < 8; ++i) {
            int tr = tbeg + 1 + 4 * i + rl;
            if (tr > segend) tr = segend;  // clamp; garbage rows never read
            st[i] = *(const f32x4*)(xb + (size_t)tr * CC + cl);
        }
        #pragma unroll
        for (int i = 0; i < 8; ++i)
            *(f32x4*)&xl[4 * i + rl][cl] = st[i];
        LDS_FENCE();                       // single wave: lgkm drain suffices
    }

    // A frags: A[mt][ch] slot (g,i) = exp(trans[16mt+c][32ch + kappa(g,i)])
    bf16x8 A[4][2];
    #pragma unroll
    for (int mt = 0; mt < 4; ++mt) {
        const float* tr = trans + (16 * mt + c) * CC;
        #pragma unroll
        for (int ch = 0; ch < 2; ++ch) {
            float4 u = *(const float4*)(tr + 32 * ch + 4 * g);
            float4 v = *(const float4*)(tr + 32 * ch + 16 + 4 * g);
            PackAB pk;
            pk.w[0] = cvtpk(__builtin_amdgcn_exp2f(u.x * L2E), __builtin_amdgcn_exp2f(u.y * L2E));
            pk.w[1] = cvtpk(__builtin_amdgcn_exp2f(u.z * L2E), __builtin_amdgcn_exp2f(u.w * L2E));
            pk.w[2] = cvtpk(__builtin_amdgcn_exp2f(v.x * L2E), __builtin_amdgcn_exp2f(v.y * L2E));
            pk.w[3] = cvtpk(__builtin_amdgcn_exp2f(v.z * L2E), __builtin_amdgcn_exp2f(v.w * L2E));
            A[mt][ch] = pk.v;
        }
    }
    // B = identity in fragment form (verified rounds 8/10/11)
    PackAB Bf[2][4];
    #pragma unroll
    for (int ch = 0; ch < 2; ++ch)
        #pragma unroll
        for (int nt = 0; nt < 4; ++nt)
            #pragma unroll
            for (int qq = 0; qq < 4; ++qq) {
                int i0 = 2 * qq, i1 = 2 * qq + 1;
                int k0 = 32 * ch + 4 * g + (i0 & 3) + 16 * (i0 >> 2);
                int k1 = 32 * ch + 4 * g + (i1 & 3) + 16 * (i1 >> 2);
                Bf[ch][nt].w[qq] = cvtpk((k0 == 16 * nt + c) ? 1.f : 0.f,
                                         (k1 == 16 * nt + c) ? 1.f : 0.f);
            }

    float Lseg = 0.f, prevS0 = 1.0f;   // first step: r=1, log2=0

    for (int idx = 0; idx < nsteps; ++idx) {
        float r_   = __builtin_amdgcn_rcpf(prevS0);
        float lgr_ = __builtin_amdgcn_logf(r_);      // log2 of ACTUAL scale
        Lseg -= lgr_;

        // x from LDS: 4x ds_read_b128, broadcast in 16-lane groups, bank-clean
        const f32x4* xr = (const f32x4*)&xl[idx][0];
        f32x4 exr[4];
        #pragma unroll
        for (int mt = 0; mt < 4; ++mt) {
            f32x4 xv = xr[4 * mt + g];
            #pragma unroll
            for (int r = 0; r < 4; ++r)
                exr[mt][r] = __builtin_amdgcn_exp2f(fmaf(xv[r], L2E, lgr_));
        }

        float ns0 = 0.f;
        #pragma unroll
        for (int nt = 0; nt < 4; ++nt) {   // D uses only Bf[*][nt] -> safe overwrite
            f32x4 Z = {0.f, 0.f, 0.f, 0.f};
            f32x4 t0, d0, d1, d2, d3;
            t0 = __builtin_amdgcn_mfma_f32_16x16x32_bf16(A[0][0], Bf[0][nt].v, Z, 0, 0, 0);
            d0 = __builtin_amdgcn_mfma_f32_16x16x32_bf16(A[0][1], Bf[1][nt].v, t0, 0, 0, 0);
            t0 = __builtin_amdgcn_mfma_f32_16x16x32_bf16(A[1][0], Bf[0][nt].v, Z, 0, 0, 0);
            d1 = __builtin_amdgcn_mfma_f32_16x16x32_bf16(A[1][1], Bf[1][nt].v, t0, 0, 0, 0);
            t0 = __builtin_amdgcn_mfma_f32_16x16x32_bf16(A[2][0], Bf[0][nt].v, Z, 0, 0, 0);
            d2 = __builtin_amdgcn_mfma_f32_16x16x32_bf16(A[2][1], Bf[1][nt].v, t0, 0, 0, 0);
            t0 = __builtin_amdgcn_mfma_f32_16x16x32_bf16(A[3][0], Bf[0][nt].v, Z, 0, 0, 0);
            d3 = __builtin_amdgcn_mfma_f32_16x16x32_bf16(A[3][1], Bf[1][nt].v, t0, 0, 0, 0);
            if (nt == 0) ns0 = d0[0];                 // raw D[0][0], pre-scale
            d0 *= exr[0]; d1 *= exr[1]; d2 *= exr[2]; d3 *= exr[3];
            Bf[0][nt].w[0] = cvtpk(d0[0], d0[1]);
            Bf[0][nt].w[1] = cvtpk(d0[2], d0[3]);
            Bf[0][nt].w[2] = cvtpk(d1[0], d1[1]);
            Bf[0][nt].w[3] = cvtpk(d1[2], d1[3]);
            Bf[1][nt].w[0] = cvtpk(d2[0], d2[1]);
            Bf[1][nt].w[1] = cvtpk(d2[2], d2[3]);
            Bf[1][nt].w[2] = cvtpk(d3[0], d3[1]);
            Bf[1][nt].w[3] = cvtpk(d3[2], d3[3]);
        }
        prevS0 = bcast0(ns0);   // lane 0 = (row 0, col 0), verified D layout
    }

    // store M_s as bf16 row-major [row][col] + Lseg
    unsigned short* Mo = Mws + (size_t)blk * 4096;
    #pragma unroll
    for (int ch = 0; ch < 2; ++ch)
        #pragma unroll
        for (int nt = 0; nt < 4; ++nt)
            #pragma unroll
            for (int e = 0; e < 8; ++e) {
                unsigned wb = (unsigned)Bf[ch][nt].w[e >> 1];
                unsigned short hb = (e & 1) ? (unsigned short)(wb >> 16)
                                            : (unsigned short)(wb & 0xffffu);
                int row = 32 * ch + 4 * g + (e & 3) + 16 * (e >> 2);
                Mo[row * 64 + 16 * nt + c] = hb;
            }
    if (l == 0) Ls[blk] = Lseg;
}

__launch_bounds__(64, 1)
__global__ void crf_apply_kernel(const float* __restrict__ x,
                                 const float* __restrict__ orig,
                                 const int*   __restrict__ lens,
                                 const unsigned short* __restrict__ Mws,
                                 const float* __restrict__ Ls,
                                 float* __restrict__ out,
                                 int T, int Pseg, int SEG) {
    const int b = blockIdx.x, j = threadIdx.x;
    __shared__ float qb[CC];
    const float L2E = 1.4426950408889634f, LN2 = 0.6931471805599453f;
    const int L = lens[b];
    const float* xb = x + (size_t)b * T * CC;

    float Mbar = (xb[0] + orig[0]) * L2E;
    float q = __builtin_amdgcn_exp2f((xb[j] + orig[j]) * L2E - Mbar);

    // 1-deep prefetch of this lane's bf16 row (row j of M_s)
    uint4 R[8];
    {
        const uint4* Ms = (const uint4*)(Mws + ((size_t)b * Pseg + 0) * 4096 + j * 64);
        #pragma unroll
        for (int i = 0; i < 8; ++i) R[i] = Ms[i];
    }

    for (int s = 0; s < Pseg; ++s) {
        int tbeg = s * SEG;
        int segend = (s + 1) * SEG; if (segend > L - 1) segend = L - 1;
        if (segend - tbeg <= 0) break;   // later segments inactive too

        uint4 Rc[8];
        #pragma unroll
        for (int i = 0; i < 8; ++i) Rc[i] = R[i];
        {   // prefetch next segment's row (clamped; garbage unused if inactive)
            int s2 = (s + 1 < Pseg) ? s + 1 : s;
            const uint4* Ms = (const uint4*)(Mws + ((size_t)b * Pseg + s2) * 4096 + j * 64);
            #pragma unroll
            for (int i = 0; i < 8; ++i) R[i] = Ms[i];
        }

        qb[j] = q;
        LDS_FENCE();

        float acc = 0.f;
        #pragma unroll
        for (int i = 0; i < 8; ++i) {
            f32x4 qv0 = *(const f32x4*)&qb[8 * i];
            f32x4 qv1 = *(const f32x4*)&qb[8 * i + 4];
            unsigned u0 = Rc[i].x, u1 = Rc[i].y, u2 = Rc[i].z, u3 = Rc[i].w;
            acc = fmaf(__uint_as_float(u0 << 16),        qv0[0], acc);
            acc = fmaf(__uint_as_float(u0 & 0xffff0000), qv0[1], acc);
            acc = fmaf(__uint_as_float(u1 << 16),        qv0[2], acc);
            acc = fmaf(__uint_as_float(u1 & 0xffff0000), qv0[3], acc);
            acc = fmaf(__uint_as_float(u2 << 16),        qv1[0], acc);
            acc = fmaf(__uint_as_float(u2 & 0xffff0000), qv1[1], acc);
            acc = fmaf(__uint_as_float(u3 << 16),        qv1[2], acc);
            acc = fmaf(__uint_as_float(u3 & 0xffff0000), qv1[3], acc);
        }
        float S = acc;
        Mbar += Ls[(size_t)b * Pseg + s];
        float p = bcast0(S);
        float r = __builtin_amdgcn_rcpf(p);
        float lgr = __builtin_amdgcn_logf(r);
        q = S * r;
        Mbar -= lgr;
        LDS_FENCE();   // reads of qb done before next overwrite
    }

    float alpha = LN2 * (Mbar + __builtin_amdgcn_logf(q));
    alpha += __shfl_xor(alpha, 1, 64);
    alpha += __shfl_xor(alpha, 2, 64);
    alpha += __shfl_xor(alpha, 4, 64);
    alpha += __shfl_xor(alpha, 8, 64);
    alpha += __shfl_xor(alpha, 16, 64);
    alpha += __shfl_xor(alpha, 32, 64);
    if (j == 0) out[b] = alpha;
}

extern "C" void kernel_launch(void* const* d_in, const int* in_sizes, int n_in,
                              void* d_out, int out_size, void* d_ws, size_t ws_size,
                              hipStream_t stream) {
    const float* x     = (const float*)d_in[0];
    const float* trans = (const float*)d_in[1];
    const float* orig  = (const float*)d_in[2];
    const int*   lens  = (const int*)d_in[3];
    float* out = (float*)d_out;

    const int B = in_sizes[3];
    const int T = in_sizes[0] / (B * CC);

    int P = 64, Pshift = 6;
    while (P > 1 && ws_size < (size_t)B * P * (4096 * 2 + 4)) { P >>= 1; --Pshift; }
    const int SEG = (T + P - 1) / P;

    unsigned short* Mws = (unsigned short*)d_ws;
    float* Ls = (float*)(Mws + (size_t)B * P * 4096);

    crf_seg_kernel<<<B * P, 64, 0, stream>>>(x, trans, lens, Mws, Ls, T, P, Pshift, SEG);
    crf_apply_kernel<<<B, 64, 0, stream>>>(x, orig, lens, Mws, Ls, out, T, P, SEG);
}